// Round 7
// baseline (166.574 us; speedup 1.0000x reference)
//
#include <hip/hip_runtime.h>
#include <math.h>

// Problem constants
#define B_ 4
#define S_ 1024
#define HID_ 1024
#define NH_ 16
#define HD_ 64
#define NTOK (B_ * S_)           // 4096

typedef __attribute__((ext_vector_type(4))) float f32x4;
typedef __attribute__((ext_vector_type(8))) short bf16x8;   // 8 bf16 = 4 VGPRs

__device__ __forceinline__ unsigned short f2bf(float f) {
    union { float f; unsigned int u; } v; v.f = f;
    unsigned int r = v.u + 0x7fffu + ((v.u >> 16) & 1u);   // RNE
    return (unsigned short)(r >> 16);
}
__device__ __forceinline__ float bf2f(unsigned short u) {
    return __uint_as_float((unsigned int)u << 16);
}

// async global->LDS, 16 B per lane. LDS dest = wave-uniform base + lane*16.
__device__ __forceinline__ void load_lds16(const void* g, void* l) {
    __builtin_amdgcn_global_load_lds(
        (const __attribute__((address_space(1))) unsigned int*)(uintptr_t)g,
        (__attribute__((address_space(3))) unsigned int*)(uintptr_t)l,
        16, 0, 0);
}

// ---------------------------------------------------------------------------
// Kernel 0: f32 -> bf16 convert for x, Wq, Wk, Wv  (unchanged)
// ---------------------------------------------------------------------------
__global__ __launch_bounds__(256) void cvt_all(
    const float* __restrict__ x, const float* __restrict__ wq,
    const float* __restrict__ wk, const float* __restrict__ wv,
    unsigned short* __restrict__ xb, unsigned short* __restrict__ wqb,
    unsigned short* __restrict__ wkb, unsigned short* __restrict__ wvb)
{
    const int which = blockIdx.y;
    const float* src = which == 0 ? x : which == 1 ? wq : which == 2 ? wk : wv;
    unsigned short* dst = which == 0 ? xb : which == 1 ? wqb : which == 2 ? wkb : wvb;
    const int n4 = (which == 0) ? (NTOK * HID_ / 4) : (HID_ * HID_ / 4);
    int i = blockIdx.x * 256 + threadIdx.x;
    if (i < n4) {
        float4 f = ((const float4*)src)[i];
        ushort4 o = make_ushort4(f2bf(f.x), f2bf(f.y), f2bf(f.z), f2bf(f.w));
        ((ushort4*)dst)[i] = o;
    }
}

// ---------------------------------------------------------------------------
// Kernel 1: QKV projection, bf16 MFMA. BK=64, XOR-swizzled LDS.
// (unchanged from round 6 — bit-identical outputs)
// ---------------------------------------------------------------------------
__global__ __launch_bounds__(256) void qkv_gemm_mfma(
    const unsigned short* __restrict__ xb,
    const unsigned short* __restrict__ Wqb, const float* __restrict__ bq,
    const unsigned short* __restrict__ Wkb, const float* __restrict__ bk,
    const unsigned short* __restrict__ Wvb, const float* __restrict__ bv,
    unsigned short* __restrict__ qout, unsigned short* __restrict__ kout,
    unsigned short* __restrict__ vtout)
{
    const int which = blockIdx.z;
    const unsigned short* __restrict__ W = which == 0 ? Wqb : which == 1 ? Wkb : Wvb;
    const float* __restrict__ bias       = which == 0 ? bq  : which == 1 ? bk  : bv;

    __shared__ unsigned short As[128 * 64];   // 16 KB, swizzled chunks
    __shared__ unsigned short Bs[128 * 64];   // 16 KB

    const int t    = threadIdx.x;
    const int lane = t & 63;
    const int w    = t >> 6;
    const int wr   = w >> 1;
    const int wc   = w & 1;
    const int g    = lane >> 4;       // quad 0..3
    const int lrow = lane & 15;

    const int bm = blockIdx.x;   // token tiles (32)
    const int bn = blockIdx.y;   // feature tiles (8)

    const unsigned short* __restrict__ Arow = (which == 2) ? W  : xb;
    const unsigned short* __restrict__ Brow = (which == 2) ? xb : W;
    const int am0 = (which == 2) ? bn * 128 : bm * 128;
    const int bn0 = (which == 2) ? bm * 128 : bn * 128;

    const int srow = t >> 3;                              // 0..31
    const int sc   = ((t & 7) ^ ((t >> 3) & 7)) << 3;     // short offset in row
    const unsigned short* gA = Arow + (size_t)(am0 + srow) * HID_ + sc;
    const unsigned short* gB = Brow + (size_t)(bn0 + srow) * HID_ + sc;

    const f32x4 zero = {0.f, 0.f, 0.f, 0.f};
    f32x4 acc[4][4];
    #pragma unroll
    for (int i = 0; i < 4; ++i)
        #pragma unroll
        for (int j = 0; j < 4; ++j) acc[i][j] = zero;

    for (int k0 = 0; k0 < HID_; k0 += 64) {
        __syncthreads();
        #pragma unroll
        for (int i = 0; i < 4; ++i) {
            load_lds16(gA + (size_t)(i * 32) * HID_ + k0, (char*)As + i * 4096 + t * 16);
            load_lds16(gB + (size_t)(i * 32) * HID_ + k0, (char*)Bs + i * 4096 + t * 16);
        }
        __syncthreads();

        #pragma unroll
        for (int ks = 0; ks < 2; ++ks) {
            bf16x8 af[4], bf[4];
            #pragma unroll
            for (int i = 0; i < 4; ++i) {
                const int row = wr * 64 + i * 16 + lrow;
                af[i] = *(const bf16x8*)&As[row * 64 + (((ks * 4 + g) ^ (row & 7)) << 3)];
            }
            #pragma unroll
            for (int j = 0; j < 4; ++j) {
                const int row = wc * 64 + j * 16 + lrow;
                bf[j] = *(const bf16x8*)&Bs[row * 64 + (((ks * 4 + g) ^ (row & 7)) << 3)];
            }
            #pragma unroll
            for (int i = 0; i < 4; ++i)
                #pragma unroll
                for (int j = 0; j < 4; ++j)
                    acc[i][j] = __builtin_amdgcn_mfma_f32_16x16x32_bf16(
                        af[i], bf[j], acc[i][j], 0, 0, 0);
        }
    }

    const int col   = lane & 15;
    const int rbase = (lane >> 4) << 2;
    if (which == 2) {
        #pragma unroll
        for (int i = 0; i < 4; ++i) {
            #pragma unroll
            for (int r = 0; r < 4; ++r) {
                const int feat = bn * 128 + wr * 64 + i * 16 + rbase + r;
                const int h = feat >> 6, d = feat & 63;
                const float bias_v = bias[feat];
                #pragma unroll
                for (int j = 0; j < 4; ++j) {
                    const int tok = bm * 128 + wc * 64 + j * 16 + col;
                    const int b = tok >> 10, s = tok & 1023;
                    vtout[((size_t)((b << 4) + h) << 16) + ((size_t)d << 10) + s] =
                        f2bf(acc[i][j][r] + bias_v);
                }
            }
        }
    } else {
        #pragma unroll
        for (int j = 0; j < 4; ++j) {
            const int feat = bn * 128 + wc * 64 + j * 16 + col;
            const int h = feat >> 6, d = feat & 63;
            const float bias_v = bias[feat];
            #pragma unroll
            for (int i = 0; i < 4; ++i) {
                const int tok0 = bm * 128 + wr * 64 + i * 16 + rbase;
                #pragma unroll
                for (int r = 0; r < 4; ++r) {
                    const int tok = tok0 + r;
                    const int b = tok >> 10, s = tok & 1023;
                    const size_t off = ((size_t)((b << 4) + h) << 16) + ((size_t)s << 6) + d;
                    const float val = acc[i][j][r] + bias_v;
                    if (which == 0) qout[off] = f2bf(val);
                    else            kout[off] = f2bf(val);
                }
            }
        }
    }
}

// ---------------------------------------------------------------------------
// Kernel 2: flash attention, bf16 MFMA, fixed-offset softmax, S^T trick,
// PLUS prefetch-behind-barrier pipeline: K/V/Ms double-buffered, ONE barrier
// per key tile, next tile's global_load_lds issued immediately after the
// barrier so the whole compute phase hides the staging latency (the next
// barrier's vmcnt(0) drain then finds the loads already complete).
// ~50 KB LDS -> 3 blocks/CU. All per-tile math identical to round 6.
// ---------------------------------------------------------------------------
__global__ __launch_bounds__(256) void attn_mfma(
    const unsigned short* __restrict__ Q, const unsigned short* __restrict__ K,
    const unsigned short* __restrict__ Vt, const float* __restrict__ mask,
    float* __restrict__ out)
{
    __shared__ unsigned short Qs[64 * 64];        //  8 KB, swizzled chunks
    __shared__ unsigned short Ks[2][64 * 64];     // 16 KB, double-buffered
    __shared__ unsigned short Vts[2][64 * 64];    // 16 KB, double-buffered [d][key]
    __shared__ unsigned short Ps[4][16 * 72];     //  9 KB, per-wave [q][key]
    __shared__ float Ms[2][64];
    __shared__ float Ls[4][16];

    const int t    = threadIdx.x;
    const int lane = t & 63;
    const int w    = t >> 6;
    const int g    = lane >> 4;      // quad 0..3
    const int ln   = lane & 15;

    const int bh = blockIdx.x;       // x-major: all q-tiles of a bh on one XCD
    const int b  = bh >> 4;
    const int h  = bh & 15;
    const int q0 = blockIdx.y << 6;

    const unsigned short* __restrict__ qg = Q  + ((size_t)bh << 16);
    const unsigned short* __restrict__ kg = K  + ((size_t)bh << 16);
    const unsigned short* __restrict__ vg = Vt + ((size_t)bh << 16);

    // Staging geometry (global-side XOR swizzle): slot G = i*256+t,
    // row = G>>3, chunk c = (G&7)^(row&7); LDS linear at slot*16 B.
    const int srow0 = t >> 3;                    // rows 0..31  (issue 0)
    const int sc0   = ((t & 7) ^ ((t >> 3) & 7));// chunk, issue-invariant (i*256: rows +32 == 0 mod 8)

    // ---- Stage Q (once) + K/V tile 0 + Ms[0] ----
    #pragma unroll
    for (int i = 0; i < 2; ++i) {
        const int row = i * 32 + srow0;
        load_lds16(qg + (size_t)(q0 + row) * 64 + sc0 * 8, (char*)Qs + i * 4096 + t * 16);
    }
    #pragma unroll
    for (int i = 0; i < 2; ++i) {
        const int row = i * 32 + srow0;
        load_lds16(kg + (size_t)row * 64 + sc0 * 8,  (char*)Ks[0]  + i * 4096 + t * 16);
        load_lds16(vg + (size_t)row * 1024 + sc0 * 8,(char*)Vts[0] + i * 4096 + t * 16);
    }
    if (t < 64) Ms[0][t] = mask[(b << 10) + t];

    const f32x4 zero = {0.f, 0.f, 0.f, 0.f};
    f32x4 O[4];
    #pragma unroll
    for (int j = 0; j < 4; ++j) O[j] = zero;
    float lacc = 0.f;

    const int qrow = w * 16 + ln;    // this thread's query row for S^T / P

    for (int kt = 0; kt < 16; ++kt) {
        const int cur = kt & 1;
        __syncthreads();   // tile kt staged & visible; prior reads of buf cur done

        // ---- prefetch tile kt+1 into the other buffer (async, no wait) ----
        float mval = 0.f;
        if (kt < 15) {
            const int nt0 = (kt + 1) << 6;
            if (t < 64) mval = mask[(b << 10) + nt0 + t];   // issued early (oldest vmcnt)
            #pragma unroll
            for (int i = 0; i < 2; ++i) {
                const int row = i * 32 + srow0;
                load_lds16(kg + (size_t)(nt0 + row) * 64 + sc0 * 8,
                           (char*)Ks[cur ^ 1]  + i * 4096 + t * 16);
                load_lds16(vg + (size_t)row * 1024 + nt0 + sc0 * 8,
                           (char*)Vts[cur ^ 1] + i * 4096 + t * 16);
            }
        }

        // ---- S^T = K Q^T  (rows=64 keys, cols=wave's 16 queries) ----
        const int kt0 = kt << 6;
        f32x4 sacc[4];
        #pragma unroll
        for (int j = 0; j < 4; ++j) sacc[j] = zero;
        #pragma unroll
        for (int ks = 0; ks < 2; ++ks) {
            bf16x8 qf = *(const bf16x8*)&Qs[qrow * 64 + (((ks * 4 + g) ^ (qrow & 7)) << 3)];
            bf16x8 kf[4];
            #pragma unroll
            for (int j = 0; j < 4; ++j) {
                const int krow = j * 16 + ln;
                kf[j] = *(const bf16x8*)&Ks[cur][krow * 64 + (((ks * 4 + g) ^ (krow & 7)) << 3)];
            }
            #pragma unroll
            for (int j = 0; j < 4; ++j)
                sacc[j] = __builtin_amdgcn_mfma_f32_16x16x32_bf16(
                    kf[j], qf, sacc[j], 0, 0, 0);
        }
        (void)kt0;

        // ---- softmax, fixed offset. Thread holds keys j*16+g*4+r, q=ln ----
        #pragma unroll
        for (int j = 0; j < 4; ++j) {
            unsigned short pb[4];
            #pragma unroll
            for (int r = 0; r < 4; ++r) {
                const int key = j * 16 + g * 4 + r;
                const float sv = sacc[j][r] * 0.125f - (2.0f - Ms[cur][key]) * 1.0e6f;
                pb[r] = f2bf(__expf(sv + 1.0e6f));
                lacc += bf2f(pb[r]);
            }
            uint2 pk;
            pk.x = (unsigned int)pb[0] | ((unsigned int)pb[1] << 16);
            pk.y = (unsigned int)pb[2] | ((unsigned int)pb[3] << 16);
            *(uint2*)&Ps[w][ln * 72 + j * 16 + (g << 2)] = pk;   // 4 consecutive keys
        }
        // wave-local P RAW: drain LDS writes before fragment reads
        asm volatile("s_waitcnt lgkmcnt(0)" ::: "memory");

        // ---- O += P V  (A=P rows q=ln contiguous, B=V^T swizzled) ----
        #pragma unroll
        for (int ks = 0; ks < 2; ++ks) {
            bf16x8 pf = *(const bf16x8*)&Ps[w][ln * 72 + ks * 32 + (g << 3)];
            bf16x8 vf[4];
            #pragma unroll
            for (int j = 0; j < 4; ++j) {
                const int vrow = j * 16 + ln;
                vf[j] = *(const bf16x8*)&Vts[cur][vrow * 64 + (((ks * 4 + g) ^ (vrow & 7)) << 3)];
            }
            #pragma unroll
            for (int j = 0; j < 4; ++j)
                O[j] = __builtin_amdgcn_mfma_f32_16x16x32_bf16(
                    pf, vf[j], O[j], 0, 0, 0);
        }

        // ---- publish next tile's mask (load was issued before the DMAs) ----
        if (kt < 15 && t < 64) Ms[cur ^ 1][t] = mval;
    }

    // Epilogue: l(q=ln) = reduce over quads; transpose via tiny LDS;
    // O C-layout: row q = g*4+r, col d = j*16+ln.
    float rs = lacc;
    rs += __shfl_xor(rs, 16);
    rs += __shfl_xor(rs, 32);
    if (lane < 16) Ls[w][ln] = rs;
    asm volatile("s_waitcnt lgkmcnt(0)" ::: "memory");
    #pragma unroll
    for (int r = 0; r < 4; ++r) {
        const float inv = 1.0f / Ls[w][(g << 2) + r];
        const int q = q0 + w * 16 + (g << 2) + r;
        const size_t base = (((size_t)(b << 10) + q) << 10) + (h << 6);
        #pragma unroll
        for (int j = 0; j < 4; ++j)
            out[base + j * 16 + ln] = O[j][r] * inv;
    }
}

// ---------------------------------------------------------------------------
extern "C" void kernel_launch(void* const* d_in, const int* in_sizes, int n_in,
                              void* d_out, int out_size, void* d_ws, size_t ws_size,
                              hipStream_t stream) {
    const float* hs   = (const float*)d_in[0];
    const float* mask = (const float*)d_in[1];
    const float* Wq   = (const float*)d_in[2];
    const float* bq   = (const float*)d_in[3];
    const float* Wk   = (const float*)d_in[4];
    const float* bk   = (const float*)d_in[5];
    const float* Wv   = (const float*)d_in[6];
    const float* bv   = (const float*)d_in[7];
    float* out = (float*)d_out;

    // Workspace: xb@0 (8MB) | wqb@8 wkb@10 wvb@12 (2MB each) |
    //            qb@14 (8MB) | kb@22 (8MB) | vtb@30 (8MB)  = 38 MB
    char* ws = (char*)d_ws;
    unsigned short* xb  = (unsigned short*)(ws);
    unsigned short* wqb = (unsigned short*)(ws + ((size_t)8  << 20));
    unsigned short* wkb = (unsigned short*)(ws + ((size_t)10 << 20));
    unsigned short* wvb = (unsigned short*)(ws + ((size_t)12 << 20));
    unsigned short* qb  = (unsigned short*)(ws + ((size_t)14 << 20));
    unsigned short* kb  = (unsigned short*)(ws + ((size_t)22 << 20));
    unsigned short* vtb = (unsigned short*)(ws + ((size_t)30 << 20));

    cvt_all<<<dim3(4096, 4), 256, 0, stream>>>(hs, Wq, Wk, Wv, xb, wqb, wkb, wvb);
    qkv_gemm_mfma<<<dim3(NTOK / 128, HID_ / 128, 3), 256, 0, stream>>>(
        xb, wqb, bq, wkb, bk, wvb, bv, qb, kb, vtb);
    attn_mfma<<<dim3(B_ * NH_, S_ / 64), 256, 0, stream>>>(qb, kb, vtb, mask, out);
}

// Round 8
// 165.006 us; speedup vs baseline: 1.0095x; 1.0095x over previous
//
#include <hip/hip_runtime.h>
#include <math.h>

// Problem constants
#define B_ 4
#define S_ 1024
#define HID_ 1024
#define NH_ 16
#define HD_ 64
#define NTOK (B_ * S_)           // 4096

typedef __attribute__((ext_vector_type(4))) float f32x4;
typedef __attribute__((ext_vector_type(8))) short bf16x8;   // 8 bf16 = 4 VGPRs

__device__ __forceinline__ unsigned short f2bf(float f) {
    union { float f; unsigned int u; } v; v.f = f;
    unsigned int r = v.u + 0x7fffu + ((v.u >> 16) & 1u);   // RNE
    return (unsigned short)(r >> 16);
}

// Packed f32->bf16 (RNE). gfx950 has v_cvt_pk_bf16_f32; fall back to software.
#if __has_builtin(__builtin_amdgcn_cvt_pk_bf16_f32)
__device__ __forceinline__ unsigned int pk_bf16(float a, float b) {
    auto v = __builtin_amdgcn_cvt_pk_bf16_f32(a, b);   // elem0=a (low), elem1=b (high)
    union { decltype(v) v; unsigned int u; } cv; cv.v = v;
    return cv.u;
}
#else
__device__ __forceinline__ unsigned int pk_bf16(float a, float b) {
    return (unsigned int)f2bf(a) | ((unsigned int)f2bf(b) << 16);
}
#endif

// async global->LDS, 16 B per lane. LDS dest = wave-uniform base + lane*16.
__device__ __forceinline__ void load_lds16(const void* g, void* l) {
    __builtin_amdgcn_global_load_lds(
        (const __attribute__((address_space(1))) unsigned int*)(uintptr_t)g,
        (__attribute__((address_space(3))) unsigned int*)(uintptr_t)l,
        16, 0, 0);
}

// ---------------------------------------------------------------------------
// Kernel 0: f32 -> bf16 convert for x, Wq, Wk, Wv  (packed cvt)
// ---------------------------------------------------------------------------
__global__ __launch_bounds__(256) void cvt_all(
    const float* __restrict__ x, const float* __restrict__ wq,
    const float* __restrict__ wk, const float* __restrict__ wv,
    unsigned short* __restrict__ xb, unsigned short* __restrict__ wqb,
    unsigned short* __restrict__ wkb, unsigned short* __restrict__ wvb)
{
    const int which = blockIdx.y;
    const float* src = which == 0 ? x : which == 1 ? wq : which == 2 ? wk : wv;
    unsigned short* dst = which == 0 ? xb : which == 1 ? wqb : which == 2 ? wkb : wvb;
    const int n4 = (which == 0) ? (NTOK * HID_ / 4) : (HID_ * HID_ / 4);
    int i = blockIdx.x * 256 + threadIdx.x;
    if (i < n4) {
        float4 f = ((const float4*)src)[i];
        uint2 o;
        o.x = pk_bf16(f.x, f.y);
        o.y = pk_bf16(f.z, f.w);
        ((uint2*)dst)[i] = o;
    }
}

// ---------------------------------------------------------------------------
// Kernel 1: QKV projection, bf16 MFMA. BK=64, XOR-swizzled LDS.
// (unchanged from round 6 — bit-identical outputs)
// ---------------------------------------------------------------------------
__global__ __launch_bounds__(256) void qkv_gemm_mfma(
    const unsigned short* __restrict__ xb,
    const unsigned short* __restrict__ Wqb, const float* __restrict__ bq,
    const unsigned short* __restrict__ Wkb, const float* __restrict__ bk,
    const unsigned short* __restrict__ Wvb, const float* __restrict__ bv,
    unsigned short* __restrict__ qout, unsigned short* __restrict__ kout,
    unsigned short* __restrict__ vtout)
{
    const int which = blockIdx.z;
    const unsigned short* __restrict__ W = which == 0 ? Wqb : which == 1 ? Wkb : Wvb;
    const float* __restrict__ bias       = which == 0 ? bq  : which == 1 ? bk  : bv;

    __shared__ unsigned short As[128 * 64];   // 16 KB, swizzled chunks
    __shared__ unsigned short Bs[128 * 64];   // 16 KB

    const int t    = threadIdx.x;
    const int lane = t & 63;
    const int w    = t >> 6;
    const int wr   = w >> 1;
    const int wc   = w & 1;
    const int g    = lane >> 4;       // quad 0..3
    const int lrow = lane & 15;

    const int bm = blockIdx.x;   // token tiles (32)
    const int bn = blockIdx.y;   // feature tiles (8)

    const unsigned short* __restrict__ Arow = (which == 2) ? W  : xb;
    const unsigned short* __restrict__ Brow = (which == 2) ? xb : W;
    const int am0 = (which == 2) ? bn * 128 : bm * 128;
    const int bn0 = (which == 2) ? bm * 128 : bn * 128;

    const int srow = t >> 3;                              // 0..31
    const int sc   = ((t & 7) ^ ((t >> 3) & 7)) << 3;     // short offset in row
    const unsigned short* gA = Arow + (size_t)(am0 + srow) * HID_ + sc;
    const unsigned short* gB = Brow + (size_t)(bn0 + srow) * HID_ + sc;

    const f32x4 zero = {0.f, 0.f, 0.f, 0.f};
    f32x4 acc[4][4];
    #pragma unroll
    for (int i = 0; i < 4; ++i)
        #pragma unroll
        for (int j = 0; j < 4; ++j) acc[i][j] = zero;

    for (int k0 = 0; k0 < HID_; k0 += 64) {
        __syncthreads();
        #pragma unroll
        for (int i = 0; i < 4; ++i) {
            load_lds16(gA + (size_t)(i * 32) * HID_ + k0, (char*)As + i * 4096 + t * 16);
            load_lds16(gB + (size_t)(i * 32) * HID_ + k0, (char*)Bs + i * 4096 + t * 16);
        }
        __syncthreads();

        #pragma unroll
        for (int ks = 0; ks < 2; ++ks) {
            bf16x8 af[4], bf[4];
            #pragma unroll
            for (int i = 0; i < 4; ++i) {
                const int row = wr * 64 + i * 16 + lrow;
                af[i] = *(const bf16x8*)&As[row * 64 + (((ks * 4 + g) ^ (row & 7)) << 3)];
            }
            #pragma unroll
            for (int j = 0; j < 4; ++j) {
                const int row = wc * 64 + j * 16 + lrow;
                bf[j] = *(const bf16x8*)&Bs[row * 64 + (((ks * 4 + g) ^ (row & 7)) << 3)];
            }
            #pragma unroll
            for (int i = 0; i < 4; ++i)
                #pragma unroll
                for (int j = 0; j < 4; ++j)
                    acc[i][j] = __builtin_amdgcn_mfma_f32_16x16x32_bf16(
                        af[i], bf[j], acc[i][j], 0, 0, 0);
        }
    }

    const int col   = lane & 15;
    const int rbase = (lane >> 4) << 2;
    if (which == 2) {
        #pragma unroll
        for (int i = 0; i < 4; ++i) {
            #pragma unroll
            for (int r = 0; r < 4; ++r) {
                const int feat = bn * 128 + wr * 64 + i * 16 + rbase + r;
                const int h = feat >> 6, d = feat & 63;
                const float bias_v = bias[feat];
                #pragma unroll
                for (int j = 0; j < 4; ++j) {
                    const int tok = bm * 128 + wc * 64 + j * 16 + col;
                    const int b = tok >> 10, s = tok & 1023;
                    vtout[((size_t)((b << 4) + h) << 16) + ((size_t)d << 10) + s] =
                        f2bf(acc[i][j][r] + bias_v);
                }
            }
        }
    } else {
        #pragma unroll
        for (int j = 0; j < 4; ++j) {
            const int feat = bn * 128 + wc * 64 + j * 16 + col;
            const int h = feat >> 6, d = feat & 63;
            const float bias_v = bias[feat];
            #pragma unroll
            for (int i = 0; i < 4; ++i) {
                const int tok0 = bm * 128 + wr * 64 + i * 16 + rbase;
                #pragma unroll
                for (int r = 0; r < 4; ++r) {
                    const int tok = tok0 + r;
                    const int b = tok >> 10, s = tok & 1023;
                    const size_t off = ((size_t)((b << 4) + h) << 16) + ((size_t)s << 6) + d;
                    const float val = acc[i][j][r] + bias_v;
                    if (which == 0) qout[off] = f2bf(val);
                    else            kout[off] = f2bf(val);
                }
            }
        }
    }
}

// ---------------------------------------------------------------------------
// Kernel 2: flash attention, bf16 MFMA, fixed-offset softmax, S^T trick.
// R6 single-buffered 2-barrier structure (R7's prefetch dbuf REVERTED: it
// cost occupancy 30->22% for zero stall reduction). New vs R6: packed
// v_cvt_pk_bf16_f32 for P (bit-identical RNE), l summed from unrounded f32 p
// (normalization shift <=2e-5 absolute).
// ---------------------------------------------------------------------------
__global__ __launch_bounds__(256) void attn_mfma(
    const unsigned short* __restrict__ Q, const unsigned short* __restrict__ K,
    const unsigned short* __restrict__ Vt, const float* __restrict__ mask,
    float* __restrict__ out)
{
    __shared__ unsigned short Qs[64 * 64];      // 8 KB, swizzled chunks
    __shared__ unsigned short Ks[64 * 64];      // 8 KB, swizzled
    __shared__ unsigned short Vts[64 * 64];     // 8 KB, swizzled  [d][key]
    __shared__ unsigned short Ps[4][16 * 72];   // 9 KB, per-wave [q][key]
    __shared__ float Ls[4][16];
    __shared__ float Ms[64];

    const int t    = threadIdx.x;
    const int lane = t & 63;
    const int w    = t >> 6;
    const int g    = lane >> 4;      // quad 0..3
    const int ln   = lane & 15;

    const int bh = blockIdx.x;       // x-major: all q-tiles of a bh on one XCD
    const int b  = bh >> 4;
    const int h  = bh & 15;
    const int q0 = blockIdx.y << 6;

    const unsigned short* __restrict__ qg = Q  + ((size_t)bh << 16);
    const unsigned short* __restrict__ kg = K  + ((size_t)bh << 16);
    const unsigned short* __restrict__ vg = Vt + ((size_t)bh << 16);

    // Stage Q tile (64 rows x 8 chunks of 16B), global-side XOR swizzle
    #pragma unroll
    for (int i = 0; i < 2; ++i) {
        const int G   = i * 256 + t;
        const int row = G >> 3;
        const int c   = (G & 7) ^ (row & 7);
        load_lds16(qg + (size_t)(q0 + row) * 64 + c * 8, (char*)Qs + i * 4096 + t * 16);
    }

    const f32x4 zero = {0.f, 0.f, 0.f, 0.f};
    f32x4 O[4];
    #pragma unroll
    for (int j = 0; j < 4; ++j) O[j] = zero;
    float lacc = 0.f;

    const int qrow = w * 16 + ln;    // this thread's query row for S^T / P

    for (int kt = 0; kt < 16; ++kt) {
        const int kt0 = kt << 6;
        __syncthreads();   // prev iter's Ks/Vts reads done
        #pragma unroll
        for (int i = 0; i < 2; ++i) {
            const int G   = i * 256 + t;
            const int row = G >> 3;
            const int c   = (G & 7) ^ (row & 7);
            load_lds16(kg + (size_t)(kt0 + row) * 64 + c * 8, (char*)Ks  + i * 4096 + t * 16);
            load_lds16(vg + (size_t)row * 1024 + kt0 + c * 8, (char*)Vts + i * 4096 + t * 16);
        }
        if (t < 64) Ms[t] = mask[(b << 10) + kt0 + t];
        __syncthreads();   // staged tiles visible

        // ---- S^T = K Q^T  (rows=64 keys, cols=wave's 16 queries) ----
        f32x4 sacc[4];
        #pragma unroll
        for (int j = 0; j < 4; ++j) sacc[j] = zero;
        #pragma unroll
        for (int ks = 0; ks < 2; ++ks) {
            bf16x8 qf = *(const bf16x8*)&Qs[qrow * 64 + (((ks * 4 + g) ^ (qrow & 7)) << 3)];
            bf16x8 kf[4];
            #pragma unroll
            for (int j = 0; j < 4; ++j) {
                const int krow = j * 16 + ln;
                kf[j] = *(const bf16x8*)&Ks[krow * 64 + (((ks * 4 + g) ^ (krow & 7)) << 3)];
            }
            #pragma unroll
            for (int j = 0; j < 4; ++j)
                sacc[j] = __builtin_amdgcn_mfma_f32_16x16x32_bf16(
                    kf[j], qf, sacc[j], 0, 0, 0);
        }

        // ---- softmax, fixed offset. Thread holds keys j*16+g*4+r, q=ln ----
        // p = exp(fl(s*0.125 - (2-mask)*1e6) + 1e6): two-step rounding
        // reproduces the reference's 0.0625 quantization at 1e6; +1e6 exact.
        #pragma unroll
        for (int j = 0; j < 4; ++j) {
            float p[4];
            #pragma unroll
            for (int r = 0; r < 4; ++r) {
                const int key = j * 16 + g * 4 + r;
                const float sv = sacc[j][r] * 0.125f - (2.0f - Ms[key]) * 1.0e6f;
                p[r] = __expf(sv + 1.0e6f);
            }
            lacc += (p[0] + p[1]) + (p[2] + p[3]);
            uint2 pk;
            pk.x = pk_bf16(p[0], p[1]);
            pk.y = pk_bf16(p[2], p[3]);
            *(uint2*)&Ps[w][ln * 72 + j * 16 + (g << 2)] = pk;   // 4 consecutive keys
        }
        // wave-local P RAW: drain LDS writes before fragment reads
        asm volatile("s_waitcnt lgkmcnt(0)" ::: "memory");

        // ---- O += P V  (A=P rows q=ln contiguous, B=V^T swizzled) ----
        #pragma unroll
        for (int ks = 0; ks < 2; ++ks) {
            bf16x8 pf = *(const bf16x8*)&Ps[w][ln * 72 + ks * 32 + (g << 3)];
            bf16x8 vf[4];
            #pragma unroll
            for (int j = 0; j < 4; ++j) {
                const int vrow = j * 16 + ln;
                vf[j] = *(const bf16x8*)&Vts[vrow * 64 + (((ks * 4 + g) ^ (vrow & 7)) << 3)];
            }
            #pragma unroll
            for (int j = 0; j < 4; ++j)
                O[j] = __builtin_amdgcn_mfma_f32_16x16x32_bf16(
                    pf, vf[j], O[j], 0, 0, 0);
        }
    }

    // Epilogue: l(q=ln) = reduce over quads; transpose via tiny LDS;
    // O C-layout: row q = g*4+r, col d = j*16+ln.
    float rs = lacc;
    rs += __shfl_xor(rs, 16);
    rs += __shfl_xor(rs, 32);
    if (lane < 16) Ls[w][ln] = rs;
    asm volatile("s_waitcnt lgkmcnt(0)" ::: "memory");
    #pragma unroll
    for (int r = 0; r < 4; ++r) {
        const float inv = 1.0f / Ls[w][(g << 2) + r];
        const int q = q0 + w * 16 + (g << 2) + r;
        const size_t base = (((size_t)(b << 10) + q) << 10) + (h << 6);
        #pragma unroll
        for (int j = 0; j < 4; ++j)
            out[base + j * 16 + ln] = O[j][r] * inv;
    }
}

// ---------------------------------------------------------------------------
extern "C" void kernel_launch(void* const* d_in, const int* in_sizes, int n_in,
                              void* d_out, int out_size, void* d_ws, size_t ws_size,
                              hipStream_t stream) {
    const float* hs   = (const float*)d_in[0];
    const float* mask = (const float*)d_in[1];
    const float* Wq   = (const float*)d_in[2];
    const float* bq   = (const float*)d_in[3];
    const float* Wk   = (const float*)d_in[4];
    const float* bk   = (const float*)d_in[5];
    const float* Wv   = (const float*)d_in[6];
    const float* bv   = (const float*)d_in[7];
    float* out = (float*)d_out;

    // Workspace: xb@0 (8MB) | wqb@8 wkb@10 wvb@12 (2MB each) |
    //            qb@14 (8MB) | kb@22 (8MB) | vtb@30 (8MB)  = 38 MB
    char* ws = (char*)d_ws;
    unsigned short* xb  = (unsigned short*)(ws);
    unsigned short* wqb = (unsigned short*)(ws + ((size_t)8  << 20));
    unsigned short* wkb = (unsigned short*)(ws + ((size_t)10 << 20));
    unsigned short* wvb = (unsigned short*)(ws + ((size_t)12 << 20));
    unsigned short* qb  = (unsigned short*)(ws + ((size_t)14 << 20));
    unsigned short* kb  = (unsigned short*)(ws + ((size_t)22 << 20));
    unsigned short* vtb = (unsigned short*)(ws + ((size_t)30 << 20));

    cvt_all<<<dim3(4096, 4), 256, 0, stream>>>(hs, Wq, Wk, Wv, xb, wqb, wkb, wvb);
    qkv_gemm_mfma<<<dim3(NTOK / 128, HID_ / 128, 3), 256, 0, stream>>>(
        xb, wqb, bq, wkb, bk, wvb, bv, qb, kb, vtb);
    attn_mfma<<<dim3(B_ * NH_, S_ / 64), 256, 0, stream>>>(qb, kb, vtb, mask, out);
}

// Round 9
// 162.678 us; speedup vs baseline: 1.0239x; 1.0143x over previous
//
#include <hip/hip_runtime.h>
#include <math.h>

// Problem constants
#define B_ 4
#define S_ 1024
#define HID_ 1024
#define NH_ 16
#define HD_ 64
#define NTOK (B_ * S_)           // 4096

typedef __attribute__((ext_vector_type(4))) float f32x4;
typedef __attribute__((ext_vector_type(8))) short bf16x8;   // 8 bf16 = 4 VGPRs

__device__ __forceinline__ unsigned short f2bf(float f) {
    union { float f; unsigned int u; } v; v.f = f;
    unsigned int r = v.u + 0x7fffu + ((v.u >> 16) & 1u);   // RNE
    return (unsigned short)(r >> 16);
}

// Packed f32->bf16 (RNE). gfx950 has v_cvt_pk_bf16_f32; fall back to software.
#if __has_builtin(__builtin_amdgcn_cvt_pk_bf16_f32)
__device__ __forceinline__ unsigned int pk_bf16(float a, float b) {
    auto v = __builtin_amdgcn_cvt_pk_bf16_f32(a, b);   // elem0=a (low), elem1=b (high)
    union { decltype(v) v; unsigned int u; } cv; cv.v = v;
    return cv.u;
}
#else
__device__ __forceinline__ unsigned int pk_bf16(float a, float b) {
    return (unsigned int)f2bf(a) | ((unsigned int)f2bf(b) << 16);
}
#endif

// async global->LDS, 16 B per lane. LDS dest = wave-uniform base + lane*16.
__device__ __forceinline__ void load_lds16(const void* g, void* l) {
    __builtin_amdgcn_global_load_lds(
        (const __attribute__((address_space(1))) unsigned int*)(uintptr_t)g,
        (__attribute__((address_space(3))) unsigned int*)(uintptr_t)l,
        16, 0, 0);
}

// ---------------------------------------------------------------------------
// Kernel 0: f32 -> bf16 convert for x, Wq, Wk, Wv  (packed cvt)
// ---------------------------------------------------------------------------
__global__ __launch_bounds__(256) void cvt_all(
    const float* __restrict__ x, const float* __restrict__ wq,
    const float* __restrict__ wk, const float* __restrict__ wv,
    unsigned short* __restrict__ xb, unsigned short* __restrict__ wqb,
    unsigned short* __restrict__ wkb, unsigned short* __restrict__ wvb)
{
    const int which = blockIdx.y;
    const float* src = which == 0 ? x : which == 1 ? wq : which == 2 ? wk : wv;
    unsigned short* dst = which == 0 ? xb : which == 1 ? wqb : which == 2 ? wkb : wvb;
    const int n4 = (which == 0) ? (NTOK * HID_ / 4) : (HID_ * HID_ / 4);
    int i = blockIdx.x * 256 + threadIdx.x;
    if (i < n4) {
        float4 f = ((const float4*)src)[i];
        uint2 o;
        o.x = pk_bf16(f.x, f.y);
        o.y = pk_bf16(f.z, f.w);
        ((uint2*)dst)[i] = o;
    }
}

// ---------------------------------------------------------------------------
// Kernel 1: QKV projection, bf16 MFMA. 128x128 tile, BK=64, XOR-swizzled LDS,
// NOW 512 threads / 8 waves (wave owns 64x32; acc 32 VGPR) -> 24 waves/CU at
// 3 blocks/CU (was 12). Per-output-element MFMA K-chain identical to R6-R8 ->
// bit-identical results. Staging: 4 DMA issues/thread, same swizzle
// (LDS pos p of a row holds global chunk p^(row&7); row stride 128 B == 0 mod
// 32 banks -> fragment reads 2-way max).
// Q,K: A=x, B=W -> [B,NH,S,HD]. V: operands SWAPPED (A=W, B=x) so the
// [B,NH,HD,S] V^T write is lane-contiguous in s.
// ---------------------------------------------------------------------------
__global__ __launch_bounds__(512, 6) void qkv_gemm_mfma(
    const unsigned short* __restrict__ xb,
    const unsigned short* __restrict__ Wqb, const float* __restrict__ bq,
    const unsigned short* __restrict__ Wkb, const float* __restrict__ bk,
    const unsigned short* __restrict__ Wvb, const float* __restrict__ bv,
    unsigned short* __restrict__ qout, unsigned short* __restrict__ kout,
    unsigned short* __restrict__ vtout)
{
    const int which = blockIdx.z;
    const unsigned short* __restrict__ W = which == 0 ? Wqb : which == 1 ? Wkb : Wvb;
    const float* __restrict__ bias       = which == 0 ? bq  : which == 1 ? bk  : bv;

    __shared__ unsigned short As[128 * 64];   // 16 KB, swizzled chunks
    __shared__ unsigned short Bs[128 * 64];   // 16 KB

    const int t    = threadIdx.x;     // 0..511
    const int lane = t & 63;
    const int w    = t >> 6;          // 0..7
    const int wr   = w >> 2;          // 0,1  : 64-row half
    const int wc   = w & 3;           // 0..3 : 32-col quarter
    const int g    = lane >> 4;       // quad 0..3
    const int lrow = lane & 15;

    const int bm = blockIdx.x;   // token tiles (32)
    const int bn = blockIdx.y;   // feature tiles (8)

    const unsigned short* __restrict__ Arow = (which == 2) ? W  : xb;
    const unsigned short* __restrict__ Brow = (which == 2) ? xb : W;
    const int am0 = (which == 2) ? bn * 128 : bm * 128;
    const int bn0 = (which == 2) ? bm * 128 : bn * 128;

    // staging: issue i covers rows i*64 + (t>>3); chunk c = (t&7)^((t>>3)&7)
    // (i*64 == 0 mod 8, so the swizzle term is issue-invariant)
    const int srow = t >> 3;                              // 0..63
    const int sc   = ((t & 7) ^ ((t >> 3) & 7)) << 3;     // short offset in row
    const unsigned short* gA = Arow + (size_t)(am0 + srow) * HID_ + sc;
    const unsigned short* gB = Brow + (size_t)(bn0 + srow) * HID_ + sc;

    const f32x4 zero = {0.f, 0.f, 0.f, 0.f};
    f32x4 acc[4][2];
    #pragma unroll
    for (int i = 0; i < 4; ++i)
        #pragma unroll
        for (int j = 0; j < 2; ++j) acc[i][j] = zero;

    for (int k0 = 0; k0 < HID_; k0 += 64) {
        __syncthreads();   // prev iter's ds_reads done before overwrite
        #pragma unroll
        for (int i = 0; i < 2; ++i) {
            load_lds16(gA + (size_t)(i * 64) * HID_ + k0, (char*)As + i * 8192 + t * 16);
            load_lds16(gB + (size_t)(i * 64) * HID_ + k0, (char*)Bs + i * 8192 + t * 16);
        }
        __syncthreads();   // staged data visible (drains vmcnt)

        #pragma unroll
        for (int ks = 0; ks < 2; ++ks) {
            bf16x8 af[4], bf[2];
            #pragma unroll
            for (int i = 0; i < 4; ++i) {
                const int row = wr * 64 + i * 16 + lrow;
                af[i] = *(const bf16x8*)&As[row * 64 + (((ks * 4 + g) ^ (row & 7)) << 3)];
            }
            #pragma unroll
            for (int j = 0; j < 2; ++j) {
                const int row = wc * 32 + j * 16 + lrow;
                bf[j] = *(const bf16x8*)&Bs[row * 64 + (((ks * 4 + g) ^ (row & 7)) << 3)];
            }
            #pragma unroll
            for (int i = 0; i < 4; ++i)
                #pragma unroll
                for (int j = 0; j < 2; ++j)
                    acc[i][j] = __builtin_amdgcn_mfma_f32_16x16x32_bf16(
                        af[i], bf[j], acc[i][j], 0, 0, 0);
        }
    }

    // Epilogue. D layout: col=lane&15 (n side), row=(lane>>4)*4+r (m side)
    const int col   = lane & 15;
    const int rbase = (lane >> 4) << 2;
    if (which == 2) {
        // m = feat (wr half), n = token (wc quarter). Lanes contiguous in s.
        #pragma unroll
        for (int i = 0; i < 4; ++i) {
            #pragma unroll
            for (int r = 0; r < 4; ++r) {
                const int feat = bn * 128 + wr * 64 + i * 16 + rbase + r;
                const int h = feat >> 6, d = feat & 63;
                const float bias_v = bias[feat];
                #pragma unroll
                for (int j = 0; j < 2; ++j) {
                    const int tok = bm * 128 + wc * 32 + j * 16 + col;
                    const int b = tok >> 10, s = tok & 1023;
                    vtout[((size_t)((b << 4) + h) << 16) + ((size_t)d << 10) + s] =
                        f2bf(acc[i][j][r] + bias_v);
                }
            }
        }
    } else {
        #pragma unroll
        for (int j = 0; j < 2; ++j) {
            const int feat = bn * 128 + wc * 32 + j * 16 + col;
            const int h = feat >> 6, d = feat & 63;
            const float bias_v = bias[feat];
            #pragma unroll
            for (int i = 0; i < 4; ++i) {
                const int tok0 = bm * 128 + wr * 64 + i * 16 + rbase;
                #pragma unroll
                for (int r = 0; r < 4; ++r) {
                    const int tok = tok0 + r;
                    const int b = tok >> 10, s = tok & 1023;
                    const size_t off = ((size_t)((b << 4) + h) << 16) + ((size_t)s << 6) + d;
                    const float val = acc[i][j][r] + bias_v;
                    if (which == 0) qout[off] = f2bf(val);
                    else            kout[off] = f2bf(val);
                }
            }
        }
    }
}

// ---------------------------------------------------------------------------
// Kernel 2: flash attention, bf16 MFMA, fixed-offset softmax, S^T trick.
// (unchanged from round 8)
// ---------------------------------------------------------------------------
__global__ __launch_bounds__(256) void attn_mfma(
    const unsigned short* __restrict__ Q, const unsigned short* __restrict__ K,
    const unsigned short* __restrict__ Vt, const float* __restrict__ mask,
    float* __restrict__ out)
{
    __shared__ unsigned short Qs[64 * 64];      // 8 KB, swizzled chunks
    __shared__ unsigned short Ks[64 * 64];      // 8 KB, swizzled
    __shared__ unsigned short Vts[64 * 64];     // 8 KB, swizzled  [d][key]
    __shared__ unsigned short Ps[4][16 * 72];   // 9 KB, per-wave [q][key]
    __shared__ float Ls[4][16];
    __shared__ float Ms[64];

    const int t    = threadIdx.x;
    const int lane = t & 63;
    const int w    = t >> 6;
    const int g    = lane >> 4;      // quad 0..3
    const int ln   = lane & 15;

    const int bh = blockIdx.x;       // x-major: all q-tiles of a bh on one XCD
    const int b  = bh >> 4;
    const int h  = bh & 15;
    const int q0 = blockIdx.y << 6;

    const unsigned short* __restrict__ qg = Q  + ((size_t)bh << 16);
    const unsigned short* __restrict__ kg = K  + ((size_t)bh << 16);
    const unsigned short* __restrict__ vg = Vt + ((size_t)bh << 16);

    // Stage Q tile (64 rows x 8 chunks of 16B), global-side XOR swizzle
    #pragma unroll
    for (int i = 0; i < 2; ++i) {
        const int G   = i * 256 + t;
        const int row = G >> 3;
        const int c   = (G & 7) ^ (row & 7);
        load_lds16(qg + (size_t)(q0 + row) * 64 + c * 8, (char*)Qs + i * 4096 + t * 16);
    }

    const f32x4 zero = {0.f, 0.f, 0.f, 0.f};
    f32x4 O[4];
    #pragma unroll
    for (int j = 0; j < 4; ++j) O[j] = zero;
    float lacc = 0.f;

    const int qrow = w * 16 + ln;    // this thread's query row for S^T / P

    for (int kt = 0; kt < 16; ++kt) {
        const int kt0 = kt << 6;
        __syncthreads();   // prev iter's Ks/Vts reads done
        #pragma unroll
        for (int i = 0; i < 2; ++i) {
            const int G   = i * 256 + t;
            const int row = G >> 3;
            const int c   = (G & 7) ^ (row & 7);
            load_lds16(kg + (size_t)(kt0 + row) * 64 + c * 8, (char*)Ks  + i * 4096 + t * 16);
            load_lds16(vg + (size_t)row * 1024 + kt0 + c * 8, (char*)Vts + i * 4096 + t * 16);
        }
        if (t < 64) Ms[t] = mask[(b << 10) + kt0 + t];
        __syncthreads();   // staged tiles visible

        // ---- S^T = K Q^T  (rows=64 keys, cols=wave's 16 queries) ----
        f32x4 sacc[4];
        #pragma unroll
        for (int j = 0; j < 4; ++j) sacc[j] = zero;
        #pragma unroll
        for (int ks = 0; ks < 2; ++ks) {
            bf16x8 qf = *(const bf16x8*)&Qs[qrow * 64 + (((ks * 4 + g) ^ (qrow & 7)) << 3)];
            bf16x8 kf[4];
            #pragma unroll
            for (int j = 0; j < 4; ++j) {
                const int krow = j * 16 + ln;
                kf[j] = *(const bf16x8*)&Ks[krow * 64 + (((ks * 4 + g) ^ (krow & 7)) << 3)];
            }
            #pragma unroll
            for (int j = 0; j < 4; ++j)
                sacc[j] = __builtin_amdgcn_mfma_f32_16x16x32_bf16(
                    kf[j], qf, sacc[j], 0, 0, 0);
        }

        // ---- softmax, fixed offset. Thread holds keys j*16+g*4+r, q=ln ----
        // p = exp(fl(s*0.125 - (2-mask)*1e6) + 1e6): two-step rounding
        // reproduces the reference's 0.0625 quantization at 1e6; +1e6 exact.
        #pragma unroll
        for (int j = 0; j < 4; ++j) {
            float p[4];
            #pragma unroll
            for (int r = 0; r < 4; ++r) {
                const int key = j * 16 + g * 4 + r;
                const float sv = sacc[j][r] * 0.125f - (2.0f - Ms[key]) * 1.0e6f;
                p[r] = __expf(sv + 1.0e6f);
            }
            lacc += (p[0] + p[1]) + (p[2] + p[3]);
            uint2 pk;
            pk.x = pk_bf16(p[0], p[1]);
            pk.y = pk_bf16(p[2], p[3]);
            *(uint2*)&Ps[w][ln * 72 + j * 16 + (g << 2)] = pk;   // 4 consecutive keys
        }
        // wave-local P RAW: drain LDS writes before fragment reads
        asm volatile("s_waitcnt lgkmcnt(0)" ::: "memory");

        // ---- O += P V  (A=P rows q=ln contiguous, B=V^T swizzled) ----
        #pragma unroll
        for (int ks = 0; ks < 2; ++ks) {
            bf16x8 pf = *(const bf16x8*)&Ps[w][ln * 72 + ks * 32 + (g << 3)];
            bf16x8 vf[4];
            #pragma unroll
            for (int j = 0; j < 4; ++j) {
                const int vrow = j * 16 + ln;
                vf[j] = *(const bf16x8*)&Vts[vrow * 64 + (((ks * 4 + g) ^ (vrow & 7)) << 3)];
            }
            #pragma unroll
            for (int j = 0; j < 4; ++j)
                O[j] = __builtin_amdgcn_mfma_f32_16x16x32_bf16(
                    pf, vf[j], O[j], 0, 0, 0);
        }
    }

    // Epilogue: l(q=ln) = reduce over quads; transpose via tiny LDS;
    // O C-layout: row q = g*4+r, col d = j*16+ln.
    float rs = lacc;
    rs += __shfl_xor(rs, 16);
    rs += __shfl_xor(rs, 32);
    if (lane < 16) Ls[w][ln] = rs;
    asm volatile("s_waitcnt lgkmcnt(0)" ::: "memory");
    #pragma unroll
    for (int r = 0; r < 4; ++r) {
        const float inv = 1.0f / Ls[w][(g << 2) + r];
        const int q = q0 + w * 16 + (g << 2) + r;
        const size_t base = (((size_t)(b << 10) + q) << 10) + (h << 6);
        #pragma unroll
        for (int j = 0; j < 4; ++j)
            out[base + j * 16 + ln] = O[j][r] * inv;
    }
}

// ---------------------------------------------------------------------------
extern "C" void kernel_launch(void* const* d_in, const int* in_sizes, int n_in,
                              void* d_out, int out_size, void* d_ws, size_t ws_size,
                              hipStream_t stream) {
    const float* hs   = (const float*)d_in[0];
    const float* mask = (const float*)d_in[1];
    const float* Wq   = (const float*)d_in[2];
    const float* bq   = (const float*)d_in[3];
    const float* Wk   = (const float*)d_in[4];
    const float* bk   = (const float*)d_in[5];
    const float* Wv   = (const float*)d_in[6];
    const float* bv   = (const float*)d_in[7];
    float* out = (float*)d_out;

    // Workspace: xb@0 (8MB) | wqb@8 wkb@10 wvb@12 (2MB each) |
    //            qb@14 (8MB) | kb@22 (8MB) | vtb@30 (8MB)  = 38 MB
    char* ws = (char*)d_ws;
    unsigned short* xb  = (unsigned short*)(ws);
    unsigned short* wqb = (unsigned short*)(ws + ((size_t)8  << 20));
    unsigned short* wkb = (unsigned short*)(ws + ((size_t)10 << 20));
    unsigned short* wvb = (unsigned short*)(ws + ((size_t)12 << 20));
    unsigned short* qb  = (unsigned short*)(ws + ((size_t)14 << 20));
    unsigned short* kb  = (unsigned short*)(ws + ((size_t)22 << 20));
    unsigned short* vtb = (unsigned short*)(ws + ((size_t)30 << 20));

    cvt_all<<<dim3(4096, 4), 256, 0, stream>>>(hs, Wq, Wk, Wv, xb, wqb, wkb, wvb);
    qkv_gemm_mfma<<<dim3(NTOK / 128, HID_ / 128, 3), 512, 0, stream>>>(
        xb, wqb, bq, wkb, bk, wvb, bv, qb, kb, vtb);
    attn_mfma<<<dim3(B_ * NH_, S_ / 64), 256, 0, stream>>>(qb, kb, vtb, mask, out);
}

// Round 10
// 154.627 us; speedup vs baseline: 1.0773x; 1.0521x over previous
//
#include <hip/hip_runtime.h>
#include <math.h>

// Problem constants
#define B_ 4
#define S_ 1024
#define HID_ 1024
#define NH_ 16
#define HD_ 64
#define NTOK (B_ * S_)           // 4096

typedef __attribute__((ext_vector_type(4))) float f32x4;
typedef __attribute__((ext_vector_type(8))) short bf16x8;   // 8 bf16 = 4 VGPRs

__device__ __forceinline__ unsigned short f2bf(float f) {
    union { float f; unsigned int u; } v; v.f = f;
    unsigned int r = v.u + 0x7fffu + ((v.u >> 16) & 1u);   // RNE
    return (unsigned short)(r >> 16);
}

// Packed f32->bf16 (RNE). gfx950 has v_cvt_pk_bf16_f32; fall back to software.
#if __has_builtin(__builtin_amdgcn_cvt_pk_bf16_f32)
__device__ __forceinline__ unsigned int pk_bf16(float a, float b) {
    auto v = __builtin_amdgcn_cvt_pk_bf16_f32(a, b);   // elem0=a (low), elem1=b (high)
    union { decltype(v) v; unsigned int u; } cv; cv.v = v;
    return cv.u;
}
#else
__device__ __forceinline__ unsigned int pk_bf16(float a, float b) {
    return (unsigned int)f2bf(a) | ((unsigned int)f2bf(b) << 16);
}
#endif

// async global->LDS, 16 B per lane. LDS dest = wave-uniform base + lane*16.
__device__ __forceinline__ void load_lds16(const void* g, void* l) {
    __builtin_amdgcn_global_load_lds(
        (const __attribute__((address_space(1))) unsigned int*)(uintptr_t)g,
        (__attribute__((address_space(3))) unsigned int*)(uintptr_t)l,
        16, 0, 0);
}

// ---------------------------------------------------------------------------
// Kernel 0: f32 -> bf16 convert for x, Wq, Wk, Wv  (packed cvt)
// ---------------------------------------------------------------------------
__global__ __launch_bounds__(256) void cvt_all(
    const float* __restrict__ x, const float* __restrict__ wq,
    const float* __restrict__ wk, const float* __restrict__ wv,
    unsigned short* __restrict__ xb, unsigned short* __restrict__ wqb,
    unsigned short* __restrict__ wkb, unsigned short* __restrict__ wvb)
{
    const int which = blockIdx.y;
    const float* src = which == 0 ? x : which == 1 ? wq : which == 2 ? wk : wv;
    unsigned short* dst = which == 0 ? xb : which == 1 ? wqb : which == 2 ? wkb : wvb;
    const int n4 = (which == 0) ? (NTOK * HID_ / 4) : (HID_ * HID_ / 4);
    int i = blockIdx.x * 256 + threadIdx.x;
    if (i < n4) {
        float4 f = ((const float4*)src)[i];
        uint2 o;
        o.x = pk_bf16(f.x, f.y);
        o.y = pk_bf16(f.z, f.w);
        ((uint2*)dst)[i] = o;
    }
}

// ---------------------------------------------------------------------------
// Kernel 1: QKV projection, bf16 MFMA. 128x128 tile, BK=64, XOR-swizzled LDS,
// 512 threads / 8 waves (wave owns 64x32). Unchanged from round 9.
// ---------------------------------------------------------------------------
__global__ __launch_bounds__(512, 6) void qkv_gemm_mfma(
    const unsigned short* __restrict__ xb,
    const unsigned short* __restrict__ Wqb, const float* __restrict__ bq,
    const unsigned short* __restrict__ Wkb, const float* __restrict__ bk,
    const unsigned short* __restrict__ Wvb, const float* __restrict__ bv,
    unsigned short* __restrict__ qout, unsigned short* __restrict__ kout,
    unsigned short* __restrict__ vtout)
{
    const int which = blockIdx.z;
    const unsigned short* __restrict__ W = which == 0 ? Wqb : which == 1 ? Wkb : Wvb;
    const float* __restrict__ bias       = which == 0 ? bq  : which == 1 ? bk  : bv;

    __shared__ unsigned short As[128 * 64];   // 16 KB, swizzled chunks
    __shared__ unsigned short Bs[128 * 64];   // 16 KB

    const int t    = threadIdx.x;     // 0..511
    const int lane = t & 63;
    const int w    = t >> 6;          // 0..7
    const int wr   = w >> 2;          // 0,1  : 64-row half
    const int wc   = w & 3;           // 0..3 : 32-col quarter
    const int g    = lane >> 4;       // quad 0..3
    const int lrow = lane & 15;

    const int bm = blockIdx.x;   // token tiles (32)
    const int bn = blockIdx.y;   // feature tiles (8)

    const unsigned short* __restrict__ Arow = (which == 2) ? W  : xb;
    const unsigned short* __restrict__ Brow = (which == 2) ? xb : W;
    const int am0 = (which == 2) ? bn * 128 : bm * 128;
    const int bn0 = (which == 2) ? bm * 128 : bn * 128;

    const int srow = t >> 3;                              // 0..63
    const int sc   = ((t & 7) ^ ((t >> 3) & 7)) << 3;     // short offset in row
    const unsigned short* gA = Arow + (size_t)(am0 + srow) * HID_ + sc;
    const unsigned short* gB = Brow + (size_t)(bn0 + srow) * HID_ + sc;

    const f32x4 zero = {0.f, 0.f, 0.f, 0.f};
    f32x4 acc[4][2];
    #pragma unroll
    for (int i = 0; i < 4; ++i)
        #pragma unroll
        for (int j = 0; j < 2; ++j) acc[i][j] = zero;

    for (int k0 = 0; k0 < HID_; k0 += 64) {
        __syncthreads();   // prev iter's ds_reads done before overwrite
        #pragma unroll
        for (int i = 0; i < 2; ++i) {
            load_lds16(gA + (size_t)(i * 64) * HID_ + k0, (char*)As + i * 8192 + t * 16);
            load_lds16(gB + (size_t)(i * 64) * HID_ + k0, (char*)Bs + i * 8192 + t * 16);
        }
        __syncthreads();   // staged data visible (drains vmcnt)

        #pragma unroll
        for (int ks = 0; ks < 2; ++ks) {
            bf16x8 af[4], bf[2];
            #pragma unroll
            for (int i = 0; i < 4; ++i) {
                const int row = wr * 64 + i * 16 + lrow;
                af[i] = *(const bf16x8*)&As[row * 64 + (((ks * 4 + g) ^ (row & 7)) << 3)];
            }
            #pragma unroll
            for (int j = 0; j < 2; ++j) {
                const int row = wc * 32 + j * 16 + lrow;
                bf[j] = *(const bf16x8*)&Bs[row * 64 + (((ks * 4 + g) ^ (row & 7)) << 3)];
            }
            #pragma unroll
            for (int i = 0; i < 4; ++i)
                #pragma unroll
                for (int j = 0; j < 2; ++j)
                    acc[i][j] = __builtin_amdgcn_mfma_f32_16x16x32_bf16(
                        af[i], bf[j], acc[i][j], 0, 0, 0);
        }
    }

    // Epilogue. D layout: col=lane&15 (n side), row=(lane>>4)*4+r (m side)
    const int col   = lane & 15;
    const int rbase = (lane >> 4) << 2;
    if (which == 2) {
        #pragma unroll
        for (int i = 0; i < 4; ++i) {
            #pragma unroll
            for (int r = 0; r < 4; ++r) {
                const int feat = bn * 128 + wr * 64 + i * 16 + rbase + r;
                const int h = feat >> 6, d = feat & 63;
                const float bias_v = bias[feat];
                #pragma unroll
                for (int j = 0; j < 2; ++j) {
                    const int tok = bm * 128 + wc * 32 + j * 16 + col;
                    const int b = tok >> 10, s = tok & 1023;
                    vtout[((size_t)((b << 4) + h) << 16) + ((size_t)d << 10) + s] =
                        f2bf(acc[i][j][r] + bias_v);
                }
            }
        }
    } else {
        #pragma unroll
        for (int j = 0; j < 2; ++j) {
            const int feat = bn * 128 + wc * 32 + j * 16 + col;
            const int h = feat >> 6, d = feat & 63;
            const float bias_v = bias[feat];
            #pragma unroll
            for (int i = 0; i < 4; ++i) {
                const int tok0 = bm * 128 + wr * 64 + i * 16 + rbase;
                #pragma unroll
                for (int r = 0; r < 4; ++r) {
                    const int tok = tok0 + r;
                    const int b = tok >> 10, s = tok & 1023;
                    const size_t off = ((size_t)((b << 4) + h) << 16) + ((size_t)s << 6) + d;
                    const float val = acc[i][j][r] + bias_v;
                    if (which == 0) qout[off] = f2bf(val);
                    else            kout[off] = f2bf(val);
                }
            }
        }
    }
}

// ---------------------------------------------------------------------------
// Kernel 2: flash attention, bf16 MFMA, fixed-offset softmax, S^T trick.
// NOW 128 queries x 8 waves (512 thr) per block: halves K/V staging DMAs and
// barrier-drain events per query vs the 64q version; per-wave inner work is
// IDENTICAL (wave owns 16 q-rows; same fragments, same K-chain) -> output
// bit-identical to rounds 8/9. Grid 64 bh x 8 qtiles = 512 blocks; LDS 52 KB
// -> 2 blocks/CU (grid-limited), 16 waves/CU.
// ---------------------------------------------------------------------------
__global__ __launch_bounds__(512, 4) void attn_mfma(
    const unsigned short* __restrict__ Q, const unsigned short* __restrict__ K,
    const unsigned short* __restrict__ Vt, const float* __restrict__ mask,
    float* __restrict__ out)
{
    __shared__ unsigned short Qs[128 * 64];     // 16 KB, swizzled chunks
    __shared__ unsigned short Ks[64 * 64];      //  8 KB, swizzled
    __shared__ unsigned short Vts[64 * 64];     //  8 KB, swizzled  [d][key]
    __shared__ unsigned short Ps[8][16 * 72];   // 18 KB, per-wave [q][key]
    __shared__ float Ls[8][16];
    __shared__ float Ms[64];

    const int t    = threadIdx.x;    // 0..511
    const int lane = t & 63;
    const int w    = t >> 6;         // 0..7
    const int g    = lane >> 4;      // quad 0..3
    const int ln   = lane & 15;

    const int bh = blockIdx.x;       // x-major: all q-tiles of a bh on one XCD
    const int b  = bh >> 4;
    const int h  = bh & 15;
    const int q0 = blockIdx.y << 7;  // 128-query tile

    const unsigned short* __restrict__ qg = Q  + ((size_t)bh << 16);
    const unsigned short* __restrict__ kg = K  + ((size_t)bh << 16);
    const unsigned short* __restrict__ vg = Vt + ((size_t)bh << 16);

    // Stage Q tile (128 rows x 8 chunks of 16B), global-side XOR swizzle
    #pragma unroll
    for (int i = 0; i < 2; ++i) {
        const int G   = i * 512 + t;
        const int row = G >> 3;                 // 0..127
        const int c   = (G & 7) ^ (row & 7);
        load_lds16(qg + (size_t)(q0 + row) * 64 + c * 8, (char*)Qs + i * 8192 + t * 16);
    }

    const f32x4 zero = {0.f, 0.f, 0.f, 0.f};
    f32x4 O[4];
    #pragma unroll
    for (int j = 0; j < 4; ++j) O[j] = zero;
    float lacc = 0.f;

    const int qrow = w * 16 + ln;    // this thread's query row (0..127)

    for (int kt = 0; kt < 16; ++kt) {
        const int kt0 = kt << 6;
        __syncthreads();   // prev iter's Ks/Vts reads done
        {
            const int row = t >> 3;             // 0..63
            const int c   = (t & 7) ^ (row & 7);
            load_lds16(kg + (size_t)(kt0 + row) * 64 + c * 8, (char*)Ks  + t * 16);
            load_lds16(vg + (size_t)row * 1024 + kt0 + c * 8, (char*)Vts + t * 16);
        }
        if (t < 64) Ms[t] = mask[(b << 10) + kt0 + t];
        __syncthreads();   // staged tiles visible

        // ---- S^T = K Q^T  (rows=64 keys, cols=wave's 16 queries) ----
        f32x4 sacc[4];
        #pragma unroll
        for (int j = 0; j < 4; ++j) sacc[j] = zero;
        #pragma unroll
        for (int ks = 0; ks < 2; ++ks) {
            bf16x8 qf = *(const bf16x8*)&Qs[qrow * 64 + (((ks * 4 + g) ^ (qrow & 7)) << 3)];
            bf16x8 kf[4];
            #pragma unroll
            for (int j = 0; j < 4; ++j) {
                const int krow = j * 16 + ln;
                kf[j] = *(const bf16x8*)&Ks[krow * 64 + (((ks * 4 + g) ^ (krow & 7)) << 3)];
            }
            #pragma unroll
            for (int j = 0; j < 4; ++j)
                sacc[j] = __builtin_amdgcn_mfma_f32_16x16x32_bf16(
                    kf[j], qf, sacc[j], 0, 0, 0);
        }

        // ---- softmax, fixed offset. Thread holds keys j*16+g*4+r, q=ln ----
        // p = exp(fl(s*0.125 - (2-mask)*1e6) + 1e6): two-step rounding
        // reproduces the reference's 0.0625 quantization at 1e6; +1e6 exact.
        #pragma unroll
        for (int j = 0; j < 4; ++j) {
            float p[4];
            #pragma unroll
            for (int r = 0; r < 4; ++r) {
                const int key = j * 16 + g * 4 + r;
                const float sv = sacc[j][r] * 0.125f - (2.0f - Ms[key]) * 1.0e6f;
                p[r] = __expf(sv + 1.0e6f);
            }
            lacc += (p[0] + p[1]) + (p[2] + p[3]);
            uint2 pk;
            pk.x = pk_bf16(p[0], p[1]);
            pk.y = pk_bf16(p[2], p[3]);
            *(uint2*)&Ps[w][ln * 72 + j * 16 + (g << 2)] = pk;   // 4 consecutive keys
        }
        // wave-local P RAW: drain LDS writes before fragment reads
        asm volatile("s_waitcnt lgkmcnt(0)" ::: "memory");

        // ---- O += P V  (A=P rows q=ln contiguous, B=V^T swizzled) ----
        #pragma unroll
        for (int ks = 0; ks < 2; ++ks) {
            bf16x8 pf = *(const bf16x8*)&Ps[w][ln * 72 + ks * 32 + (g << 3)];
            bf16x8 vf[4];
            #pragma unroll
            for (int j = 0; j < 4; ++j) {
                const int vrow = j * 16 + ln;
                vf[j] = *(const bf16x8*)&Vts[vrow * 64 + (((ks * 4 + g) ^ (vrow & 7)) << 3)];
            }
            #pragma unroll
            for (int j = 0; j < 4; ++j)
                O[j] = __builtin_amdgcn_mfma_f32_16x16x32_bf16(
                    pf, vf[j], O[j], 0, 0, 0);
        }
    }

    // Epilogue: l(q=ln) = reduce over quads; transpose via tiny LDS;
    // O C-layout: row q = g*4+r, col d = j*16+ln.
    float rs = lacc;
    rs += __shfl_xor(rs, 16);
    rs += __shfl_xor(rs, 32);
    if (lane < 16) Ls[w][ln] = rs;
    asm volatile("s_waitcnt lgkmcnt(0)" ::: "memory");
    #pragma unroll
    for (int r = 0; r < 4; ++r) {
        const float inv = 1.0f / Ls[w][(g << 2) + r];
        const int q = q0 + w * 16 + (g << 2) + r;
        const size_t base = (((size_t)(b << 10) + q) << 10) + (h << 6);
        #pragma unroll
        for (int j = 0; j < 4; ++j)
            out[base + j * 16 + ln] = O[j][r] * inv;
    }
}

// ---------------------------------------------------------------------------
extern "C" void kernel_launch(void* const* d_in, const int* in_sizes, int n_in,
                              void* d_out, int out_size, void* d_ws, size_t ws_size,
                              hipStream_t stream) {
    const float* hs   = (const float*)d_in[0];
    const float* mask = (const float*)d_in[1];
    const float* Wq   = (const float*)d_in[2];
    const float* bq   = (const float*)d_in[3];
    const float* Wk   = (const float*)d_in[4];
    const float* bk   = (const float*)d_in[5];
    const float* Wv   = (const float*)d_in[6];
    const float* bv   = (const float*)d_in[7];
    float* out = (float*)d_out;

    // Workspace: xb@0 (8MB) | wqb@8 wkb@10 wvb@12 (2MB each) |
    //            qb@14 (8MB) | kb@22 (8MB) | vtb@30 (8MB)  = 38 MB
    char* ws = (char*)d_ws;
    unsigned short* xb  = (unsigned short*)(ws);
    unsigned short* wqb = (unsigned short*)(ws + ((size_t)8  << 20));
    unsigned short* wkb = (unsigned short*)(ws + ((size_t)10 << 20));
    unsigned short* wvb = (unsigned short*)(ws + ((size_t)12 << 20));
    unsigned short* qb  = (unsigned short*)(ws + ((size_t)14 << 20));
    unsigned short* kb  = (unsigned short*)(ws + ((size_t)22 << 20));
    unsigned short* vtb = (unsigned short*)(ws + ((size_t)30 << 20));

    cvt_all<<<dim3(4096, 4), 256, 0, stream>>>(hs, Wq, Wk, Wv, xb, wqb, wkb, wvb);
    qkv_gemm_mfma<<<dim3(NTOK / 128, HID_ / 128, 3), 512, 0, stream>>>(
        xb, wqb, bq, wkb, bk, wvb, bv, qb, kb, vtb);
    attn_mfma<<<dim3(B_ * NH_, S_ / 128), 512, 0, stream>>>(qb, kb, vtb, mask, out);
}

// Round 12
// 154.556 us; speedup vs baseline: 1.0778x; 1.0005x over previous
//
#include <hip/hip_runtime.h>
#include <math.h>

// Problem constants
#define B_ 4
#define S_ 1024
#define HID_ 1024
#define NH_ 16
#define HD_ 64
#define NTOK (B_ * S_)           // 4096

typedef __attribute__((ext_vector_type(4))) float f32x4;
typedef __attribute__((ext_vector_type(8))) short bf16x8;   // 8 bf16 = 4 VGPRs

__device__ __forceinline__ unsigned short f2bf(float f) {
    union { float f; unsigned int u; } v; v.f = f;
    unsigned int r = v.u + 0x7fffu + ((v.u >> 16) & 1u);   // RNE
    return (unsigned short)(r >> 16);
}

// Packed f32->bf16 (RNE). gfx950 has v_cvt_pk_bf16_f32; fall back to software.
#if __has_builtin(__builtin_amdgcn_cvt_pk_bf16_f32)
__device__ __forceinline__ unsigned int pk_bf16(float a, float b) {
    auto v = __builtin_amdgcn_cvt_pk_bf16_f32(a, b);   // elem0=a (low), elem1=b (high)
    union { decltype(v) v; unsigned int u; } cv; cv.v = v;
    return cv.u;
}
#else
__device__ __forceinline__ unsigned int pk_bf16(float a, float b) {
    return (unsigned int)f2bf(a) | ((unsigned int)f2bf(b) << 16);
}
#endif

// async global->LDS, 16 B per lane. LDS dest = wave-uniform base + lane*16.
__device__ __forceinline__ void load_lds16(const void* g, void* l) {
    __builtin_amdgcn_global_load_lds(
        (const __attribute__((address_space(1))) unsigned int*)(uintptr_t)g,
        (__attribute__((address_space(3))) unsigned int*)(uintptr_t)l,
        16, 0, 0);
}

// ---------------------------------------------------------------------------
// Kernel 0: f32 -> bf16 convert for x, Wq, Wk, Wv  (packed cvt)
// ---------------------------------------------------------------------------
__global__ __launch_bounds__(256) void cvt_all(
    const float* __restrict__ x, const float* __restrict__ wq,
    const float* __restrict__ wk, const float* __restrict__ wv,
    unsigned short* __restrict__ xb, unsigned short* __restrict__ wqb,
    unsigned short* __restrict__ wkb, unsigned short* __restrict__ wvb)
{
    const int which = blockIdx.y;
    const float* src = which == 0 ? x : which == 1 ? wq : which == 2 ? wk : wv;
    unsigned short* dst = which == 0 ? xb : which == 1 ? wqb : which == 2 ? wkb : wvb;
    const int n4 = (which == 0) ? (NTOK * HID_ / 4) : (HID_ * HID_ / 4);
    int i = blockIdx.x * 256 + threadIdx.x;
    if (i < n4) {
        float4 f = ((const float4*)src)[i];
        uint2 o;
        o.x = pk_bf16(f.x, f.y);
        o.y = pk_bf16(f.z, f.w);
        ((uint2*)dst)[i] = o;
    }
}

// ---------------------------------------------------------------------------
// Kernel 1: QKV projection, bf16 MFMA. 128x128 tile, BK=64, XOR-swizzled LDS,
// 512 threads / 8 waves (wave owns 64x32). Unchanged from rounds 9/10.
// ---------------------------------------------------------------------------
__global__ __launch_bounds__(512, 6) void qkv_gemm_mfma(
    const unsigned short* __restrict__ xb,
    const unsigned short* __restrict__ Wqb, const float* __restrict__ bq,
    const unsigned short* __restrict__ Wkb, const float* __restrict__ bk,
    const unsigned short* __restrict__ Wvb, const float* __restrict__ bv,
    unsigned short* __restrict__ qout, unsigned short* __restrict__ kout,
    unsigned short* __restrict__ vtout)
{
    const int which = blockIdx.z;
    const unsigned short* __restrict__ W = which == 0 ? Wqb : which == 1 ? Wkb : Wvb;
    const float* __restrict__ bias       = which == 0 ? bq  : which == 1 ? bk  : bv;

    __shared__ unsigned short As[128 * 64];   // 16 KB, swizzled chunks
    __shared__ unsigned short Bs[128 * 64];   // 16 KB

    const int t    = threadIdx.x;     // 0..511
    const int lane = t & 63;
    const int w    = t >> 6;          // 0..7
    const int wr   = w >> 2;          // 0,1  : 64-row half
    const int wc   = w & 3;           // 0..3 : 32-col quarter
    const int g    = lane >> 4;       // quad 0..3
    const int lrow = lane & 15;

    const int bm = blockIdx.x;   // token tiles (32)
    const int bn = blockIdx.y;   // feature tiles (8)

    const unsigned short* __restrict__ Arow = (which == 2) ? W  : xb;
    const unsigned short* __restrict__ Brow = (which == 2) ? xb : W;
    const int am0 = (which == 2) ? bn * 128 : bm * 128;
    const int bn0 = (which == 2) ? bm * 128 : bn * 128;

    const int srow = t >> 3;                              // 0..63
    const int sc   = ((t & 7) ^ ((t >> 3) & 7)) << 3;     // short offset in row
    const unsigned short* gA = Arow + (size_t)(am0 + srow) * HID_ + sc;
    const unsigned short* gB = Brow + (size_t)(bn0 + srow) * HID_ + sc;

    const f32x4 zero = {0.f, 0.f, 0.f, 0.f};
    f32x4 acc[4][2];
    #pragma unroll
    for (int i = 0; i < 4; ++i)
        #pragma unroll
        for (int j = 0; j < 2; ++j) acc[i][j] = zero;

    for (int k0 = 0; k0 < HID_; k0 += 64) {
        __syncthreads();   // prev iter's ds_reads done before overwrite
        #pragma unroll
        for (int i = 0; i < 2; ++i) {
            load_lds16(gA + (size_t)(i * 64) * HID_ + k0, (char*)As + i * 8192 + t * 16);
            load_lds16(gB + (size_t)(i * 64) * HID_ + k0, (char*)Bs + i * 8192 + t * 16);
        }
        __syncthreads();   // staged data visible (drains vmcnt)

        #pragma unroll
        for (int ks = 0; ks < 2; ++ks) {
            bf16x8 af[4], bf[2];
            #pragma unroll
            for (int i = 0; i < 4; ++i) {
                const int row = wr * 64 + i * 16 + lrow;
                af[i] = *(const bf16x8*)&As[row * 64 + (((ks * 4 + g) ^ (row & 7)) << 3)];
            }
            #pragma unroll
            for (int j = 0; j < 2; ++j) {
                const int row = wc * 32 + j * 16 + lrow;
                bf[j] = *(const bf16x8*)&Bs[row * 64 + (((ks * 4 + g) ^ (row & 7)) << 3)];
            }
            #pragma unroll
            for (int i = 0; i < 4; ++i)
                #pragma unroll
                for (int j = 0; j < 2; ++j)
                    acc[i][j] = __builtin_amdgcn_mfma_f32_16x16x32_bf16(
                        af[i], bf[j], acc[i][j], 0, 0, 0);
        }
    }

    // Epilogue. D layout: col=lane&15 (n side), row=(lane>>4)*4+r (m side)
    const int col   = lane & 15;
    const int rbase = (lane >> 4) << 2;
    if (which == 2) {
        #pragma unroll
        for (int i = 0; i < 4; ++i) {
            #pragma unroll
            for (int r = 0; r < 4; ++r) {
                const int feat = bn * 128 + wr * 64 + i * 16 + rbase + r;
                const int h = feat >> 6, d = feat & 63;
                const float bias_v = bias[feat];
                #pragma unroll
                for (int j = 0; j < 2; ++j) {
                    const int tok = bm * 128 + wc * 32 + j * 16 + col;
                    const int b = tok >> 10, s = tok & 1023;
                    vtout[((size_t)((b << 4) + h) << 16) + ((size_t)d << 10) + s] =
                        f2bf(acc[i][j][r] + bias_v);
                }
            }
        }
    } else {
        #pragma unroll
        for (int j = 0; j < 2; ++j) {
            const int feat = bn * 128 + wc * 32 + j * 16 + col;
            const int h = feat >> 6, d = feat & 63;
            const float bias_v = bias[feat];
            #pragma unroll
            for (int i = 0; i < 4; ++i) {
                const int tok0 = bm * 128 + wr * 64 + i * 16 + rbase;
                #pragma unroll
                for (int r = 0; r < 4; ++r) {
                    const int tok = tok0 + r;
                    const int b = tok >> 10, s = tok & 1023;
                    const size_t off = ((size_t)((b << 4) + h) << 16) + ((size_t)s << 6) + d;
                    const float val = acc[i][j][r] + bias_v;
                    if (which == 0) qout[off] = f2bf(val);
                    else            kout[off] = f2bf(val);
                }
            }
        }
    }
}

// ---------------------------------------------------------------------------
// Kernel 2: flash attention, bf16 MFMA, fixed-offset softmax, S^T trick.
// 128 queries x 8 waves per block; KT=128 (two 64-key sub-tiles per barrier
// pair, barriers halved vs R10) — NOW LEGAL: Q lives in REGISTERS (each
// thread's S^T operand Q[qrow][ks*32+g*8..+7] = 2 global_load_dwordx4 loaded
// once, reused across all 16 key tiles), freeing the 16 KB Qs buffer.
// LDS = Ks 16 + Vts 16 + Ps 18 + misc ~= 51.5 KB < 64 KB workgroup cap.
// Key processing order and all per-element ops unchanged -> bit-identical
// to rounds 8-10. Grid 64 bh x 8 qtiles = 512 blocks, 2 blocks/CU.
// ---------------------------------------------------------------------------
__global__ __launch_bounds__(512, 4) void attn_mfma(
    const unsigned short* __restrict__ Q, const unsigned short* __restrict__ K,
    const unsigned short* __restrict__ Vt, const float* __restrict__ mask,
    float* __restrict__ out)
{
    __shared__ unsigned short Ks[2][64 * 64];   // 16 KB, sub-tile pair
    __shared__ unsigned short Vts[2][64 * 64];  // 16 KB, sub-tile pair [d][key]
    __shared__ unsigned short Ps[8][16 * 72];   // 18 KB, per-wave [q][key]
    __shared__ float Ls[8][16];
    __shared__ float Ms2[128];

    const int t    = threadIdx.x;    // 0..511
    const int lane = t & 63;
    const int w    = t >> 6;         // 0..7
    const int g    = lane >> 4;      // quad 0..3
    const int ln   = lane & 15;

    const int bh = blockIdx.x;       // x-major: all q-tiles of a bh on one XCD
    const int b  = bh >> 4;
    const int h  = bh & 15;
    const int q0 = blockIdx.y << 7;  // 128-query tile

    const unsigned short* __restrict__ qg = Q  + ((size_t)bh << 16);
    const unsigned short* __restrict__ kg = K  + ((size_t)bh << 16);
    const unsigned short* __restrict__ vg = Vt + ((size_t)bh << 16);

    const int qrow = w * 16 + ln;    // this thread's query row (0..127)

    // ---- Q operand in registers: Q[q0+qrow][ks*32 + g*8 .. +7], loaded once
    bf16x8 qreg[2];
    #pragma unroll
    for (int ks = 0; ks < 2; ++ks)
        qreg[ks] = *(const bf16x8*)&qg[(size_t)(q0 + qrow) * 64 + ks * 32 + (g << 3)];

    const f32x4 zero = {0.f, 0.f, 0.f, 0.f};
    f32x4 O[4];
    #pragma unroll
    for (int j = 0; j < 4; ++j) O[j] = zero;
    float lacc = 0.f;

    for (int kt2 = 0; kt2 < 8; ++kt2) {
        const int kt0 = kt2 << 7;    // base key of the 128-key pair
        __syncthreads();   // prev iter's Ks/Vts reads done
        {
            const int row = t >> 3;             // 0..63
            const int c   = (t & 7) ^ (row & 7);
            #pragma unroll
            for (int s = 0; s < 2; ++s) {
                const int kb0 = kt0 + (s << 6);
                load_lds16(kg + (size_t)(kb0 + row) * 64 + c * 8, (char*)Ks[s]  + t * 16);
                load_lds16(vg + (size_t)row * 1024 + kb0 + c * 8, (char*)Vts[s] + t * 16);
            }
        }
        if (t < 128) Ms2[t] = mask[(b << 10) + kt0 + t];
        __syncthreads();   // staged tiles visible

        #pragma unroll
        for (int s = 0; s < 2; ++s) {
            // ---- S^T = K Q^T  (rows=64 keys, cols=wave's 16 queries) ----
            f32x4 sacc[4];
            #pragma unroll
            for (int j = 0; j < 4; ++j) sacc[j] = zero;
            #pragma unroll
            for (int ks = 0; ks < 2; ++ks) {
                bf16x8 kf[4];
                #pragma unroll
                for (int j = 0; j < 4; ++j) {
                    const int krow = j * 16 + ln;
                    kf[j] = *(const bf16x8*)&Ks[s][krow * 64 + (((ks * 4 + g) ^ (krow & 7)) << 3)];
                }
                #pragma unroll
                for (int j = 0; j < 4; ++j)
                    sacc[j] = __builtin_amdgcn_mfma_f32_16x16x32_bf16(
                        kf[j], qreg[ks], sacc[j], 0, 0, 0);
            }

            // ---- softmax, fixed offset. Thread holds keys j*16+g*4+r, q=ln ----
            // p = exp(fl(s*0.125 - (2-mask)*1e6) + 1e6): two-step rounding
            // reproduces the reference's 0.0625 quantization at 1e6; +1e6 exact.
            #pragma unroll
            for (int j = 0; j < 4; ++j) {
                float p[4];
                #pragma unroll
                for (int r = 0; r < 4; ++r) {
                    const int key = j * 16 + g * 4 + r;
                    const float sv = sacc[j][r] * 0.125f - (2.0f - Ms2[(s << 6) + key]) * 1.0e6f;
                    p[r] = __expf(sv + 1.0e6f);
                }
                lacc += (p[0] + p[1]) + (p[2] + p[3]);
                uint2 pk;
                pk.x = pk_bf16(p[0], p[1]);
                pk.y = pk_bf16(p[2], p[3]);
                *(uint2*)&Ps[w][ln * 72 + j * 16 + (g << 2)] = pk;   // 4 consecutive keys
            }
            // wave-local P RAW: drain LDS writes before fragment reads
            asm volatile("s_waitcnt lgkmcnt(0)" ::: "memory");

            // ---- O += P V  (A=P rows q=ln contiguous, B=V^T swizzled) ----
            #pragma unroll
            for (int ks = 0; ks < 2; ++ks) {
                bf16x8 pf = *(const bf16x8*)&Ps[w][ln * 72 + ks * 32 + (g << 3)];
                bf16x8 vf[4];
                #pragma unroll
                for (int j = 0; j < 4; ++j) {
                    const int vrow = j * 16 + ln;
                    vf[j] = *(const bf16x8*)&Vts[s][vrow * 64 + (((ks * 4 + g) ^ (vrow & 7)) << 3)];
                }
                #pragma unroll
                for (int j = 0; j < 4; ++j)
                    O[j] = __builtin_amdgcn_mfma_f32_16x16x32_bf16(
                        pf, vf[j], O[j], 0, 0, 0);
            }
        }
    }

    // Epilogue: l(q=ln) = reduce over quads; transpose via tiny LDS;
    // O C-layout: row q = g*4+r, col d = j*16+ln.
    float rs = lacc;
    rs += __shfl_xor(rs, 16);
    rs += __shfl_xor(rs, 32);
    if (lane < 16) Ls[w][ln] = rs;
    asm volatile("s_waitcnt lgkmcnt(0)" ::: "memory");
    #pragma unroll
    for (int r = 0; r < 4; ++r) {
        const float inv = 1.0f / Ls[w][(g << 2) + r];
        const int q = q0 + w * 16 + (g << 2) + r;
        const size_t base = (((size_t)(b << 10) + q) << 10) + (h << 6);
        #pragma unroll
        for (int j = 0; j < 4; ++j)
            out[base + j * 16 + ln] = O[j][r] * inv;
    }
}

// ---------------------------------------------------------------------------
extern "C" void kernel_launch(void* const* d_in, const int* in_sizes, int n_in,
                              void* d_out, int out_size, void* d_ws, size_t ws_size,
                              hipStream_t stream) {
    const float* hs   = (const float*)d_in[0];
    const float* mask = (const float*)d_in[1];
    const float* Wq   = (const float*)d_in[2];
    const float* bq   = (const float*)d_in[3];
    const float* Wk   = (const float*)d_in[4];
    const float* bk   = (const float*)d_in[5];
    const float* Wv   = (const float*)d_in[6];
    const float* bv   = (const float*)d_in[7];
    float* out = (float*)d_out;

    // Workspace: xb@0 (8MB) | wqb@8 wkb@10 wvb@12 (2MB each) |
    //            qb@14 (8MB) | kb@22 (8MB) | vtb@30 (8MB)  = 38 MB
    char* ws = (char*)d_ws;
    unsigned short* xb  = (unsigned short*)(ws);
    unsigned short* wqb = (unsigned short*)(ws + ((size_t)8  << 20));
    unsigned short* wkb = (unsigned short*)(ws + ((size_t)10 << 20));
    unsigned short* wvb = (unsigned short*)(ws + ((size_t)12 << 20));
    unsigned short* qb  = (unsigned short*)(ws + ((size_t)14 << 20));
    unsigned short* kb  = (unsigned short*)(ws + ((size_t)22 << 20));
    unsigned short* vtb = (unsigned short*)(ws + ((size_t)30 << 20));

    cvt_all<<<dim3(4096, 4), 256, 0, stream>>>(hs, Wq, Wk, Wv, xb, wqb, wkb, wvb);
    qkv_gemm_mfma<<<dim3(NTOK / 128, HID_ / 128, 3), 512, 0, stream>>>(
        xb, wqb, bq, wkb, bk, wvb, bv, qb, kb, vtb);
    attn_mfma<<<dim3(B_ * NH_, S_ / 128), 512, 0, stream>>>(qb, kb, vtb, mask, out);
}